// Round 1
// baseline (378.052 us; speedup 1.0000x reference)
//
#include <hip/hip_runtime.h>

typedef int int32x4 __attribute__((ext_vector_type(4)));

// ---------------------------------------------------------------------------
// maxabs reduction (for weight_scale = max|W| / 7)
// ---------------------------------------------------------------------------
__global__ void maxabs_kernel(const float* __restrict__ x, int n4,
                              unsigned* __restrict__ out) {
    float m = 0.f;
    int i = blockIdx.x * blockDim.x + threadIdx.x;
    int stride = gridDim.x * blockDim.x;
    const float4* x4 = (const float4*)x;
    for (int j = i; j < n4; j += stride) {
        float4 v = x4[j];
        m = fmaxf(m, fmaxf(fmaxf(fabsf(v.x), fabsf(v.y)),
                           fmaxf(fabsf(v.z), fabsf(v.w))));
    }
#pragma unroll
    for (int off = 32; off; off >>= 1)
        m = fmaxf(m, __shfl_down(m, off, 64));
    __shared__ float wm[4];
    int ln = threadIdx.x & 63, wv = threadIdx.x >> 6;
    if (ln == 0) wm[wv] = m;
    __syncthreads();
    if (threadIdx.x == 0) {
        float bm = fmaxf(fmaxf(wm[0], wm[1]), fmaxf(wm[2], wm[3]));
        // nonnegative floats: uint bit order == float order
        atomicMax(out, __float_as_uint(bm));
    }
}

// ---------------------------------------------------------------------------
// fake-quant to int8 codes: clip(round(x / s), lo, hi), packed 4/thread
// sptr[0]/sdiv is the scale (sdiv=7 for weights where sptr holds maxabs)
// ---------------------------------------------------------------------------
__global__ void quant_kernel(const float* __restrict__ x, int n4,
                             const float* __restrict__ sptr, float sdiv,
                             float lo, float hi, char* __restrict__ out) {
    float s = sptr[0] / sdiv;
    int i = blockIdx.x * blockDim.x + threadIdx.x;
    int stride = gridDim.x * blockDim.x;
    const float4* x4 = (const float4*)x;
    int* o4 = (int*)out;
    for (int j = i; j < n4; j += stride) {
        float4 v = x4[j];
        int a = (int)fminf(fmaxf(rintf(v.x / s), lo), hi);
        int b = (int)fminf(fmaxf(rintf(v.y / s), lo), hi);
        int c = (int)fminf(fmaxf(rintf(v.z / s), lo), hi);
        int d = (int)fminf(fmaxf(rintf(v.w / s), lo), hi);
        o4[j] = (a & 255) | ((b & 255) << 8) | ((c & 255) << 16) | ((d & 255) << 24);
    }
}

// ---------------------------------------------------------------------------
// int8 GEMM, C[m,n] = sum_k A[m,k]*B[n,k]  (both row-major [.,K], "B^T" form)
// 128x128 tile, BK=128 bytes, 4 waves (2x2), 4x4 16x16x64 fragments/wave.
// global_load_lds width=16 with pre-swizzled global source; XOR-swizzled
// ds_read_b128 (chunk ^= row&7) -> 2-way bank conflicts only (free, m136).
// FIRST epilogue:  h = sab*acc + rintf(bias/sab)*sab; relu;
//                  store clip(round(h/s2),0,15) as int8 (the h_q codes).
// !FIRST epilogue: out_f32 = sab*acc + rintf(bias/sab)*sab.
// ---------------------------------------------------------------------------
template <bool FIRST>
__global__ __launch_bounds__(256, 2)
void gemm_i8_kernel(const char* __restrict__ A, const char* __restrict__ B,
                    int M, int N, int K,
                    const float* __restrict__ sa_ptr,
                    const float* __restrict__ wmax_ptr,
                    const float* __restrict__ bias,
                    const float* __restrict__ s2_ptr,
                    char* __restrict__ out8, float* __restrict__ outf) {
    __shared__ __align__(16) char lA[128 * 128];
    __shared__ __align__(16) char lB[128 * 128];

    const int tid = threadIdx.x;
    const int wv = tid >> 6, ln = tid & 63;
    const int m0 = blockIdx.y * 128;
    const int n0 = blockIdx.x * 128;
    const int wr = wv >> 1, wc = wv & 1;

    int32x4 acc[4][4] = {};

    const int nkt = K >> 7;
    for (int kt = 0; kt < nkt; ++kt) {
        const int k0 = kt << 7;
        // ---- stage A and B tiles (16 KiB each) ----
#pragma unroll
        for (int r = 0; r < 4; ++r) {
            int s = r * 256 + tid;     // 16B slot index 0..1023
            int row = s >> 3;          // 8 slots per 128B row
            int ch = s & 7;
            int sch = ch ^ (row & 7);  // pre-swizzle the SOURCE (m173)
            long ga = (long)(m0 + row) * K + k0 + sch * 16;
            long gb = (long)(n0 + row) * K + k0 + sch * 16;
            int lbase = (r * 256 + wv * 64) * 16;  // wave-uniform LDS base
            __builtin_amdgcn_global_load_lds(
                (const __attribute__((address_space(1))) void*)(A + ga),
                (__attribute__((address_space(3))) void*)(lA + lbase), 16, 0, 0);
            __builtin_amdgcn_global_load_lds(
                (const __attribute__((address_space(1))) void*)(B + gb),
                (__attribute__((address_space(3))) void*)(lB + lbase), 16, 0, 0);
        }
        __syncthreads();

        // ---- LDS -> fragments (swizzled read) ----
        int32x4 af[4][2], bf[4][2];
#pragma unroll
        for (int mf = 0; mf < 4; ++mf)
#pragma unroll
            for (int kk = 0; kk < 2; ++kk) {
                int row = wr * 64 + mf * 16 + (ln & 15);
                int ch = kk * 4 + (ln >> 4);
                af[mf][kk] = *(const int32x4*)(lA + row * 128 + ((ch ^ (row & 7)) * 16));
            }
#pragma unroll
        for (int nf = 0; nf < 4; ++nf)
#pragma unroll
            for (int kk = 0; kk < 2; ++kk) {
                int col = wc * 64 + nf * 16 + (ln & 15);
                int ch = kk * 4 + (ln >> 4);
                bf[nf][kk] = *(const int32x4*)(lB + col * 128 + ((ch ^ (col & 7)) * 16));
            }

        // ---- MFMA ----
#pragma unroll
        for (int kk = 0; kk < 2; ++kk)
#pragma unroll
            for (int mf = 0; mf < 4; ++mf)
#pragma unroll
                for (int nf = 0; nf < 4; ++nf)
                    acc[mf][nf] = __builtin_amdgcn_mfma_i32_16x16x64_i8(
                        af[mf][kk], bf[nf][kk], acc[mf][nf], 0, 0, 0);
        __syncthreads();
    }

    // ---- epilogue ----
    float sa = sa_ptr[0];
    float sw = wmax_ptr[0] / 7.0f;  // weight_scale
    float sab = sa * sw;
    float s2 = FIRST ? s2_ptr[0] : 0.f;

#pragma unroll
    for (int nf = 0; nf < 4; ++nf) {
        int col = n0 + wc * 64 + nf * 16 + (ln & 15);
        float bq = rintf(bias[col] / sab) * sab;  // Int32Bias fake-quant
#pragma unroll
        for (int mf = 0; mf < 4; ++mf) {
            int rbase = m0 + wr * 64 + mf * 16 + ((ln >> 4) << 2);
#pragma unroll
            for (int i = 0; i < 4; ++i) {
                float h = sab * (float)acc[mf][nf][i] + bq;
                long off = (long)(rbase + i) * N + col;
                if constexpr (FIRST) {
                    h = fmaxf(h, 0.f);
                    float q = fminf(fmaxf(rintf(h / s2), 0.f), 15.f);
                    out8[off] = (char)(int)q;
                } else {
                    outf[off] = h;
                }
            }
        }
    }
}

// ---------------------------------------------------------------------------
// launch
// ---------------------------------------------------------------------------
extern "C" void kernel_launch(void* const* d_in, const int* in_sizes, int n_in,
                              void* d_out, int out_size, void* d_ws, size_t ws_size,
                              hipStream_t stream) {
    const float* x  = (const float*)d_in[0];   // [4,2048,2048] -> [8192,2048]
    const float* W1 = (const float*)d_in[1];   // [8192,2048]
    const float* b1 = (const float*)d_in[2];   // [8192]
    const float* W2 = (const float*)d_in[3];   // [2048,8192]
    const float* b2 = (const float*)d_in[4];   // [2048]
    const float* s1 = (const float*)d_in[5];
    const float* s2 = (const float*)d_in[6];

    const int M = 8192, D = 2048, F = 8192;

    char* ws = (char*)d_ws;
    unsigned* mx1 = (unsigned*)ws;        // maxabs(W1) as float bits
    unsigned* mx2 = (unsigned*)(ws + 4);  // maxabs(W2)
    char* xq  = ws + 256;                  // [M,D]  int8
    char* w1q = xq + (size_t)M * D;        // [F,D]  int8
    char* w2q = w1q + (size_t)F * D;       // [D,F]  int8
    char* hq  = w2q + (size_t)D * F;       // [M,F]  int8 (h_q codes 0..15)
    // total ws use: 256 + 3*16.78MB + 67.1MB ~= 117.4 MB

    hipMemsetAsync(d_ws, 0, 8, stream);  // zero the maxabs slots

    maxabs_kernel<<<2048, 256, 0, stream>>>(W1, (F * D) >> 2, mx1);
    maxabs_kernel<<<2048, 256, 0, stream>>>(W2, (D * F) >> 2, mx2);

    quant_kernel<<<2048, 256, 0, stream>>>(x,  (M * D) >> 2, s1, 1.f, -8.f, 7.f, xq);
    quant_kernel<<<2048, 256, 0, stream>>>(W1, (F * D) >> 2, (const float*)mx1, 7.f, -8.f, 7.f, w1q);
    quant_kernel<<<2048, 256, 0, stream>>>(W2, (D * F) >> 2, (const float*)mx2, 7.f, -8.f, 7.f, w2q);

    // h_q = clip(round(relu(x_q W1_q^T + b1_q)/s2),0,15)  -> int8 codes
    gemm_i8_kernel<true><<<dim3(F / 128, M / 128), 256, 0, stream>>>(
        xq, w1q, M, F, D, s1, (const float*)mx1, b1, s2, hq, nullptr);

    // out = s2*sw2 * (h_int W2_int^T) + b2_q
    gemm_i8_kernel<false><<<dim3(D / 128, M / 128), 256, 0, stream>>>(
        hq, w2q, M, D, F, s2, (const float*)mx2, b2, nullptr, nullptr, (float*)d_out);
}